// Round 17
// baseline (254.867 us; speedup 1.0000x reference)
//
#include <hip/hip_runtime.h>
#include <hip/hip_bf16.h>
#include <math.h>

#define NFEATS 128
#define NHID   64
#define NCLS   40
#define NEG_SLOPE 0.01f

#define GSH_S  9                // log2(stage group span)
#define GSPAN_S 512             // nodes per stage group
#define GCAP_S 9216             // staged capacity per group (mean 8192, +11 sigma)
#define SB     2048             // edges per stage block (8/thread at 256 threads)
#define GCAP_Q 2816             // staged2 capacity per quarter (mean 2048, +17 sigma)

typedef float f32x4 __attribute__((ext_vector_type(4)));
typedef int   i32x2 __attribute__((ext_vector_type(2)));

// bf16 helpers (raw ushort storage, RNE rounding)
__device__ inline unsigned short f2bfu(float v) {
    union { float f; unsigned int u; } x; x.f = v;
    unsigned int r = (x.u + 0x7FFFu + ((x.u >> 16) & 1u)) >> 16;
    return (unsigned short)r;
}
__device__ inline float bf2f(unsigned short u) {
    union { unsigned int u32; float f; } x; x.u32 = ((unsigned int)u) << 16;
    return x.f;
}
__device__ inline float bflo(unsigned int u) {
    union { unsigned int v; float f; } x; x.v = u << 16; return x.f;
}
__device__ inline float bfhi(unsigned int u) {
    union { unsigned int v; float f; } x; x.v = u & 0xFFFF0000u; return x.f;
}

// ---- role split: interleave nA blocks with nB blocks (1:1 striping, then tail) ----
__device__ inline void role_split(int i, int nA, int nB, int* ia, int* ib) {
    *ia = -1; *ib = -1;
    int m2 = 2 * min(nA, nB);
    if (i < m2) { if (i & 1) *ib = i >> 1; else *ia = i >> 1; }
    else if (nA > nB) *ia = i - nB;
    else *ib = i - nA;
}

// ---------------- K2: staged binning (issue-early loads, split atomic/store) + GEMM1 ----------------

__global__ __launch_bounds__(256) void stage_gemm1_kernel(
    const int* __restrict__ srcA, const int* __restrict__ dstA, const float* __restrict__ ew,
    int* __restrict__ gcur, int2* __restrict__ staged, int E, int nStage, int ngrp,
    const float* __restrict__ x, const float* __restrict__ W1, const float* __restrict__ b1,
    float* __restrict__ h1, int n, int nTile) {
    __shared__ __align__(16) float Ws[64 * 64];   // 16KB; stage role aliases as int[512]

    int ia, ib;
    role_split(blockIdx.x, nStage, nTile, &ia, &ib);
    int tid = threadIdx.x;

    if (ia >= 0) {
        int* hist = (int*)Ws;         // [256] (ngrp<=256)
        int* wcur = ((int*)Ws) + 256; // [256]
        if (tid < 256) hist[tid] = 0;
        __syncthreads();

        int q0 = (ia * SB) >> 2;                 // int4-quad base
        int qend = min(q0 + SB / 4, E >> 2);
        int dcache[8], scache[8];
        float wcache[8];

        // pass A: issue ALL loads early; histogram on dst
#pragma unroll
        for (int it = 0; it < 2; ++it) {
            int q = q0 + it * 256 + tid;
            bool ok = (q < qend);
            int4 d4 = ok ? ((const int4*)dstA)[q] : make_int4(-1, -1, -1, -1);
            int4 s4 = ok ? ((const int4*)srcA)[q] : make_int4(0, 0, 0, 0);
            float4 w4 = ok ? ((const float4*)ew)[q] : make_float4(0, 0, 0, 0);
            dcache[it * 4 + 0] = d4.x; dcache[it * 4 + 1] = d4.y;
            dcache[it * 4 + 2] = d4.z; dcache[it * 4 + 3] = d4.w;
            scache[it * 4 + 0] = s4.x; scache[it * 4 + 1] = s4.y;
            scache[it * 4 + 2] = s4.z; scache[it * 4 + 3] = s4.w;
            wcache[it * 4 + 0] = w4.x; wcache[it * 4 + 1] = w4.y;
            wcache[it * 4 + 2] = w4.z; wcache[it * 4 + 3] = w4.w;
#pragma unroll
            for (int j = 0; j < 4; ++j)
                if (dcache[it * 4 + j] >= 0) atomicAdd(&hist[dcache[it * 4 + j] >> GSH_S], 1);
        }
        if (ia == nStage - 1) {
            for (int e = (E & ~3) + tid; e < E; e += 256) atomicAdd(&hist[dstA[e] >> GSH_S], 1);
        }
        __syncthreads();

        // reserve per-group regions
        if (tid < ngrp) {
            int c = hist[tid];
            wcur[tid] = (c > 0) ? atomicAdd(&gcur[tid], c) : 0;
        }
        __syncthreads();

        // pass B phase 1: 8 independent LDS cursor atomics
        int pos[8];
#pragma unroll
        for (int j = 0; j < 8; ++j) {
            int d = dcache[j];
            pos[j] = (d >= 0) ? atomicAdd(&wcur[d >> GSH_S], 1) : GCAP_S;
        }
        // pass B phase 2: stores
#pragma unroll
        for (int j = 0; j < 8; ++j) {
            int d = dcache[j];
            if (d >= 0 && pos[j] < GCAP_S)
                staged[(size_t)(d >> GSH_S) * GCAP_S + pos[j]] =
                    make_int2(((d & (GSPAN_S - 1)) << 17) | scache[j], __float_as_int(wcache[j]));
        }
        if (ia == nStage - 1) {
            for (int e = (E & ~3) + tid; e < E; e += 256) {
                int d = dstA[e];
                int g = d >> GSH_S;
                int p = atomicAdd(&wcur[g], 1);
                if (p < GCAP_S)
                    staged[(size_t)g * GCAP_S + p] =
                        make_int2(((d & (GSPAN_S - 1)) << 17) | srcA[e], __float_as_int(ew[e]));
            }
        }
        return;
    }

    // ---- gemm role: h1 = lrelu(x @ W1 + b1), 64x64 tile, 4x4 micro-tile ----
    int c4 = (tid & 15) * 4;
    int r0 = ib * 64 + (tid >> 4) * 4;
    int rr[4];
#pragma unroll
    for (int i = 0; i < 4; ++i) rr[i] = min(r0 + i, n - 1);

    float acc[4][4] = {};
    for (int ph = 0; ph < 2; ++ph) {
        __syncthreads();
        for (int i = tid; i < 64 * 16; i += 256)
            ((float4*)Ws)[i] = ((const float4*)W1)[ph * 1024 + i];
        __syncthreads();
#pragma unroll 2
        for (int kk = 0; kk < 64; kk += 4) {
            f32x4 av[4], bv[4];
#pragma unroll
            for (int i = 0; i < 4; ++i)
                av[i] = __builtin_nontemporal_load(
                    (const f32x4*)&x[(size_t)rr[i] * NFEATS + ph * 64 + kk]);
#pragma unroll
            for (int q = 0; q < 4; ++q) bv[q] = *(const f32x4*)&Ws[(kk + q) * 64 + c4];
#pragma unroll
            for (int i = 0; i < 4; ++i) {
#pragma unroll
                for (int q = 0; q < 4; ++q) {
                    float a = av[i][q];
#pragma unroll
                    for (int j = 0; j < 4; ++j) acc[i][j] += a * bv[q][j];
                }
            }
        }
    }

#pragma unroll
    for (int i = 0; i < 4; ++i) {
        int rw = r0 + i;
        if (rw >= n) break;
        float4 o;
        float* oa = (float*)&o;
#pragma unroll
        for (int j = 0; j < 4; ++j) {
            float v = acc[i][j] + b1[c4 + j];
            oa[j] = (v > 0.0f) ? v : v * NEG_SLOPE;
        }
        *(float4*)&h1[(size_t)rw * 64 + c4] = o;
    }
}

// ---------------- K3: deg/dis + node-sort, 4 quarter-blocks per stage group ----------------
// Block b: g = b>>2, quarter q = b&3 (nodes g*512 + q*128 .. +127). Scans the parent
// group's record list, filters to its 128-node window, LDS deg/hist, scan, scatter into
// its own staged2 region (blockIdx * GCAP_Q). Records stay (src, ew).

__global__ __launch_bounds__(256) void degsort_kernel(
    const int* __restrict__ gcur, const int2* __restrict__ staged,
    int2* __restrict__ staged2, float* __restrict__ dis,
    int2* __restrict__ nodeptr, int n) {
    __shared__ float deg[128];
    __shared__ int hist[128], basearr[128], cur[128];

    int tid = threadIdx.x;
    int g = blockIdx.x >> 2;
    int qtr = blockIdx.x & 3;

    if (tid < 128) { deg[tid] = 0.0f; hist[tid] = 0; }
    __syncthreads();

    int cnt = min(gcur[g], GCAP_S);
    const int2* sl = staged + (size_t)g * GCAP_S;

    // pass 1: filter + deg/hist accumulate
    for (int i = tid; i < cnt; i += 256) {
        int2 r = sl[i];
        int dl = r.x >> 17;
        if ((dl >> 7) == qtr) {
            atomicAdd(&deg[dl & 127], __int_as_float(r.y));
            atomicAdd(&hist[dl & 127], 1);
        }
    }
    __syncthreads();

    int node = g * GSPAN_S + qtr * 128 + tid;
    if (tid < 128 && node < n) dis[node] = rsqrtf(1.0f + deg[tid]);

    // exclusive scan of hist[128]
    if (tid < 128) basearr[tid] = hist[tid];
    __syncthreads();
    for (int off = 1; off < 128; off <<= 1) {
        int t_ = 0;
        if (tid < 128 && tid >= off) t_ = basearr[tid - off];
        __syncthreads();
        if (tid < 128) basearr[tid] += t_;
        __syncthreads();
    }
    int qbase = blockIdx.x * GCAP_Q;
    if (tid < 128) {
        int ex = basearr[tid] - hist[tid];
        cur[tid] = ex;
        if (node < n) nodeptr[node] = make_int2(qbase + ex, hist[tid]);
    }
    __syncthreads();

    // pass 2: scatter records into quarter region
    int2* out = staged2 + qbase;
    for (int i = tid; i < cnt; i += 256) {
        int2 r = sl[i];
        int dl = r.x >> 17;
        if ((dl >> 7) == qtr) {
            int pos = atomicAdd(&cur[dl & 127], 1);
            out[pos] = make_int2(r.x & 0x1FFFF, r.y);
        }
    }
}

// ---------------- K4: GEMM2 standalone: t1' = dis ⊙ (h1 @ Wc1) -> bf16 ----------------

__global__ __launch_bounds__(256) void gemm2s_kernel(
    const float* __restrict__ in, const float* __restrict__ W, const float* __restrict__ dis,
    unsigned short* __restrict__ outp, int n) {
    __shared__ __align__(16) float Ws[NHID * 64];
    int tid = threadIdx.x;
    for (int i = tid; i < NHID * 16; i += 256) ((float4*)Ws)[i] = ((const float4*)W)[i];
    __syncthreads();

    int c4 = (tid & 15) * 4;
    int r0 = blockIdx.x * 64 + (tid >> 4) * 4;
    int rr[4];
#pragma unroll
    for (int i = 0; i < 4; ++i) rr[i] = min(r0 + i, n - 1);

    float acc[4][4] = {};
#pragma unroll 2
    for (int kk = 0; kk < NHID; kk += 4) {
        f32x4 av[4], bv[4];
#pragma unroll
        for (int i = 0; i < 4; ++i)
            av[i] = __builtin_nontemporal_load((const f32x4*)&in[(size_t)rr[i] * NHID + kk]);
#pragma unroll
        for (int q = 0; q < 4; ++q) bv[q] = *(const f32x4*)&Ws[(kk + q) * 64 + c4];
#pragma unroll
        for (int i = 0; i < 4; ++i) {
#pragma unroll
            for (int q = 0; q < 4; ++q) {
                float a = av[i][q];
#pragma unroll
                for (int j = 0; j < 4; ++j) acc[i][j] += a * bv[q][j];
            }
        }
    }

#pragma unroll
    for (int i = 0; i < 4; ++i) {
        int rw = r0 + i;
        if (rw >= n) break;
        float dr = dis[rw];
        ushort4 o;
        o.x = f2bfu(dr * acc[i][0]); o.y = f2bfu(dr * acc[i][1]);
        o.z = f2bfu(dr * acc[i][2]); o.w = f2bfu(dr * acc[i][3]);
        *(ushort4*)&outp[(size_t)rw * 64 + c4] = o;
    }
}

// ---------------- K5/K6: aggregation — 16-lane group per edge, 4 edges per load-round ----------------

template <int LAYER>
__global__ __launch_bounds__(256) void agg_kernel(const int2* __restrict__ nodeptr,
                                                  const int2* __restrict__ recs0,
                                                  const unsigned short* __restrict__ tb,
                                                  const float* __restrict__ dis,
                                                  const float* __restrict__ bias,
                                                  unsigned short* __restrict__ outp, int n) {
    int wv = threadIdx.x >> 6;
    int lane = threadIdx.x & 63;
    int node = blockIdx.x * 4 + wv;
    if (node >= n) return;

    int2 np = nodeptr[node];
    int start = np.x, c = np.y;
    int grp = lane >> 4;
    int r16 = lane & 15;
    float di = dis[node];

    f32x4 a0 = {0, 0, 0, 0}, a1 = {0, 0, 0, 0}, a2 = {0, 0, 0, 0}, a3 = {0, 0, 0, 0};

    // self term (weight 1): row already pre-scaled by dis[node]
    if (grp == 0) {
        uint2 uv = *(const uint2*)&tb[(size_t)node * NHID + r16 * 4];
        a0[0] += bflo(uv.x); a0[1] += bfhi(uv.x);
        a0[2] += bflo(uv.y); a0[3] += bfhi(uv.y);
    }

    const i32x2* recs = (const i32x2*)(recs0 + start);
    for (int b = 0; b < c; b += 64) {
        int rem = min(64, c - b);
        i32x2 ent = (lane < rem) ? recs[b + lane] : (i32x2){0, 0};
        for (int k = 0; k < rem; k += 16) {
            int e0 = k + grp, e1 = k + 4 + grp, e2 = k + 8 + grp, e3 = k + 12 + grp;
            int s0 = __shfl(ent[0], e0); float w0 = __int_as_float(__shfl(ent[1], e0));
            int s1 = __shfl(ent[0], e1); float w1 = __int_as_float(__shfl(ent[1], e1));
            int s2 = __shfl(ent[0], e2); float w2 = __int_as_float(__shfl(ent[1], e2));
            int s3 = __shfl(ent[0], e3); float w3 = __int_as_float(__shfl(ent[1], e3));
            uint2 u0 = *(const uint2*)&tb[(size_t)s0 * NHID + r16 * 4];
            uint2 u1 = *(const uint2*)&tb[(size_t)s1 * NHID + r16 * 4];
            uint2 u2 = *(const uint2*)&tb[(size_t)s2 * NHID + r16 * 4];
            uint2 u3 = *(const uint2*)&tb[(size_t)s3 * NHID + r16 * 4];
            a0[0] += w0 * bflo(u0.x); a0[1] += w0 * bfhi(u0.x);
            a0[2] += w0 * bflo(u0.y); a0[3] += w0 * bfhi(u0.y);
            a1[0] += w1 * bflo(u1.x); a1[1] += w1 * bfhi(u1.x);
            a1[2] += w1 * bflo(u1.y); a1[3] += w1 * bfhi(u1.y);
            a2[0] += w2 * bflo(u2.x); a2[1] += w2 * bfhi(u2.x);
            a2[2] += w2 * bflo(u2.y); a2[3] += w2 * bfhi(u2.y);
            a3[0] += w3 * bflo(u3.x); a3[1] += w3 * bfhi(u3.x);
            a3[2] += w3 * bflo(u3.y); a3[3] += w3 * bfhi(u3.y);
        }
    }

    f32x4 acc;
#pragma unroll
    for (int j = 0; j < 4; ++j) acc[j] = (a0[j] + a1[j]) + (a2[j] + a3[j]);
#pragma unroll
    for (int j = 0; j < 4; ++j) {
        acc[j] += __shfl_xor(acc[j], 16);
        acc[j] += __shfl_xor(acc[j], 32);
    }

    if (lane < 16) {
        ushort4 o;
        unsigned short* op = (unsigned short*)&o;
#pragma unroll
        for (int j = 0; j < 4; ++j) {
            float v;
            if (LAYER == 1) {
                v = di * acc[j] + bias[r16 * 4 + j];
                v = (v > 0.0f) ? v : v * NEG_SLOPE;
                v *= di;                        // pre-scale for next layer
            } else {
                v = di * acc[j];
            }
            op[j] = f2bfu(v);
        }
        *(ushort4*)&outp[(size_t)node * NHID + r16 * 4] = o;
    }
}

// ---------------- K7: tail — h3 = lrelu(u2@Wc2+bc2); out = log_softmax(h3@Wo+bo) ----------------

__global__ __launch_bounds__(256) void tail_kernel(const unsigned short* __restrict__ ub,
                                                   const float* __restrict__ Wc2,
                                                   const float* __restrict__ bc2,
                                                   const float* __restrict__ Wo,
                                                   const float* __restrict__ bo,
                                                   float* __restrict__ outp, int n) {
    __shared__ __align__(16) float WsA[NHID * 64];           // 16KB: Wc2 then Wo(2560)
    __shared__ __align__(16) unsigned short hs[64 * 68];     // 8.7KB bf16 h3
    __shared__ float bos[NCLS];

    int tid = threadIdx.x;
    for (int i = tid; i < NHID * 16; i += 256) ((float4*)WsA)[i] = ((const float4*)Wc2)[i];
    __syncthreads();

    int c4 = (tid & 15) * 4;
    int r0l = (tid >> 4) * 4;
    int base = blockIdx.x * 64;

    int rr[4];
#pragma unroll
    for (int i = 0; i < 4; ++i) rr[i] = min(base + r0l + i, n - 1);

    float acc[4][4] = {};
#pragma unroll 2
    for (int kk = 0; kk < NHID; kk += 4) {
        f32x4 av[4], bv[4];
#pragma unroll
        for (int i = 0; i < 4; ++i) {
            ushort4 uv = *(const ushort4*)&ub[(size_t)rr[i] * NHID + kk];
            av[i][0] = bf2f(uv.x); av[i][1] = bf2f(uv.y);
            av[i][2] = bf2f(uv.z); av[i][3] = bf2f(uv.w);
        }
#pragma unroll
        for (int q = 0; q < 4; ++q) bv[q] = *(const f32x4*)&WsA[(kk + q) * 64 + c4];
#pragma unroll
        for (int i = 0; i < 4; ++i) {
#pragma unroll
            for (int q = 0; q < 4; ++q) {
                float a = av[i][q];
#pragma unroll
                for (int j = 0; j < 4; ++j) acc[i][j] += a * bv[q][j];
            }
        }
    }

#pragma unroll
    for (int i = 0; i < 4; ++i) {
#pragma unroll
        for (int j = 0; j < 4; ++j) {
            float v = acc[i][j] + bc2[c4 + j];
            v = (v > 0.0f) ? v : v * NEG_SLOPE;
            hs[(r0l + i) * 68 + c4 + j] = f2bfu(v);
        }
    }
    __syncthreads();

    // reload WsA[0..2559] = Wo (64x40)
    for (int i = tid; i < NHID * NCLS / 4; i += 256) ((float4*)WsA)[i] = ((const float4*)Wo)[i];
    if (tid < NCLS) bos[tid] = bo[tid];
    __syncthreads();

    // phase 2: row = tid>>2 (0..63), cols c0..c0+9
    int row = tid >> 2;
    int c0 = (tid & 3) * 10;
    int node = base + row;

    float z[10];
#pragma unroll
    for (int j = 0; j < 10; ++j) z[j] = 0.0f;

#pragma unroll 2
    for (int k0 = 0; k0 < NHID; k0 += 4) {
        ushort4 hv = *(const ushort4*)&hs[row * 68 + k0];
        float h0 = bf2f(hv.x), h1 = bf2f(hv.y), h2 = bf2f(hv.z), h3 = bf2f(hv.w);
        const float* w0 = &WsA[(k0 + 0) * NCLS + c0];
        const float* w1 = &WsA[(k0 + 1) * NCLS + c0];
        const float* w2 = &WsA[(k0 + 2) * NCLS + c0];
        const float* w3 = &WsA[(k0 + 3) * NCLS + c0];
#pragma unroll
        for (int j = 0; j < 10; ++j)
            z[j] += h0 * w0[j] + h1 * w1[j] + h2 * w2[j] + h3 * w3[j];
    }
#pragma unroll
    for (int j = 0; j < 10; ++j) z[j] += bos[c0 + j];

    float m = z[0];
#pragma unroll
    for (int j = 1; j < 10; ++j) m = fmaxf(m, z[j]);
    m = fmaxf(m, __shfl_xor(m, 1));
    m = fmaxf(m, __shfl_xor(m, 2));

    float s = 0.0f;
#pragma unroll
    for (int j = 0; j < 10; ++j) s += expf(z[j] - m);
    s += __shfl_xor(s, 1);
    s += __shfl_xor(s, 2);
    float ls = logf(s);

    if (node < n) {
#pragma unroll
        for (int j = 0; j < 10; ++j)
            outp[(size_t)node * NCLS + c0 + j] = z[j] - m - ls;
    }
}

// ---------------- launch ----------------

extern "C" void kernel_launch(void* const* d_in, const int* in_sizes, int n_in,
                              void* d_out, int out_size, void* d_ws, size_t ws_size,
                              hipStream_t stream) {
    const float* x   = (const float*)d_in[0];
    const int*   ei  = (const int*)d_in[1];   // [2, E] flat
    const float* ew  = (const float*)d_in[2];
    const float* W1  = (const float*)d_in[3];
    const float* b1  = (const float*)d_in[4];
    const float* Wc1 = (const float*)d_in[5];
    const float* bc1 = (const float*)d_in[6];
    const float* Wc2 = (const float*)d_in[7];
    const float* bc2 = (const float*)d_in[8];
    const float* Wo  = (const float*)d_in[9];
    const float* bo  = (const float*)d_in[10];
    float* out = (float*)d_out;

    const int N = in_sizes[0] / NFEATS;
    const int E = in_sizes[1] / 2;
    const int* src = ei;
    const int* dst = ei + E;

    const int ngrp   = (N + GSPAN_S - 1) >> GSH_S;    // 196
    const int nSort  = ngrp * 4;                      // 784 quarter-blocks
    const int nStage = (E + SB - 1) / SB;             // 782
    const int nTile  = (N + 63) / 64;                 // 1563
    const int aggBlocks = (N + 3) / 4;

    // workspace layout (~84 MB)
    float*          bufA  = (float*)d_ws;                          // N*64 f32 (h1)
    unsigned short* t1b   = (unsigned short*)(bufA + (size_t)N * NHID);  // N*64 bf16 (t1', later u2)
    unsigned short* h2b   = t1b + (size_t)N * NHID;                // N*64 bf16 (h2')
    int2*  staged  = (int2*)(h2b + (size_t)N * NHID);              // ngrp*GCAP_S
    int2*  staged2 = staged + (size_t)ngrp * GCAP_S;               // nSort*GCAP_Q
    float* dis     = (float*)(staged2 + (size_t)nSort * GCAP_Q);   // N
    int*   gcur    = (int*)(dis + N);                              // ngrp (pad to 8B)
    int2*  nodeptr = (int2*)(gcur + ((ngrp + 1) & ~1));            // N

    // K1: zero group cursors
    hipMemsetAsync(gcur, 0, ngrp * sizeof(int), stream);

    // K2: coarse staged binning + h1 = lrelu(x@W1+b1) -> bufA
    stage_gemm1_kernel<<<nStage + nTile, 256, 0, stream>>>(
        src, dst, ew, gcur, staged, E, nStage, ngrp, x, W1, b1, bufA, N, nTile);

    // K3: deg/dis + node-sort (4 quarter-blocks per group) -> staged2, nodeptr
    degsort_kernel<<<nSort, 256, 0, stream>>>(gcur, staged, staged2, dis, nodeptr, N);

    // K4: t1' = dis ⊙ (h1@Wc1) -> t1b (bf16)
    gemm2s_kernel<<<nTile, 256, 0, stream>>>(bufA, Wc1, dis, t1b, N);

    // K5: h2' = dis ⊙ lrelu(dis*(agg) + bc1) -> h2b (bf16)
    agg_kernel<1><<<aggBlocks, 256, 0, stream>>>(nodeptr, staged2, t1b, dis, bc1, h2b, N);

    // K6: u2 = dis*(agg(h2')) -> t1b reused (bf16)
    agg_kernel<2><<<aggBlocks, 256, 0, stream>>>(nodeptr, staged2, h2b, dis, nullptr, t1b, N);

    // K7: tail
    tail_kernel<<<nTile, 256, 0, stream>>>(t1b, Wc2, bc2, Wo, bo, out, N);
}

// Round 18
// 232.905 us; speedup vs baseline: 1.0943x; 1.0943x over previous
//
#include <hip/hip_runtime.h>
#include <hip/hip_bf16.h>
#include <math.h>

#define NFEATS 128
#define NHID   64
#define NCLS   40
#define NEG_SLOPE 0.01f

#define GSH_S  9                // log2(stage group span)
#define GSPAN_S 512             // nodes per stage group
#define GCAP_S 9216             // staged capacity per group (mean 8192, +11 sigma)
#define SB     2048             // edges per stage block (8/thread at 256 threads)
#define FIXSCALE 17179869184.0f /* 2^34 */
#define CNTSH  44

typedef float f32x4 __attribute__((ext_vector_type(4)));
typedef int   i32x2 __attribute__((ext_vector_type(2)));

// bf16 helpers (raw ushort storage, RNE rounding)
__device__ inline unsigned short f2bfu(float v) {
    union { float f; unsigned int u; } x; x.f = v;
    unsigned int r = (x.u + 0x7FFFu + ((x.u >> 16) & 1u)) >> 16;
    return (unsigned short)r;
}
__device__ inline float bf2f(unsigned short u) {
    union { unsigned int u32; float f; } x; x.u32 = ((unsigned int)u) << 16;
    return x.f;
}
__device__ inline float bflo(unsigned int u) {
    union { unsigned int v; float f; } x; x.v = u << 16; return x.f;
}
__device__ inline float bfhi(unsigned int u) {
    union { unsigned int v; float f; } x; x.v = u & 0xFFFF0000u; return x.f;
}

// ---- role split: interleave nA blocks with nB blocks (1:1 striping, then tail) ----
__device__ inline void role_split(int i, int nA, int nB, int* ia, int* ib) {
    *ia = -1; *ib = -1;
    int m2 = 2 * min(nA, nB);
    if (i < m2) { if (i & 1) *ib = i >> 1; else *ia = i >> 1; }
    else if (nA > nB) *ia = i - nB;
    else *ib = i - nA;
}

// ---------------- K2: staged binning (issue-early loads, split atomic/store) + GEMM1 ----------------

__global__ __launch_bounds__(256) void stage_gemm1_kernel(
    const int* __restrict__ srcA, const int* __restrict__ dstA, const float* __restrict__ ew,
    int* __restrict__ gcur, int2* __restrict__ staged, int E, int nStage, int ngrp,
    const float* __restrict__ x, const float* __restrict__ W1, const float* __restrict__ b1,
    float* __restrict__ h1, int n, int nTile) {
    __shared__ __align__(16) float Ws[64 * 64];   // 16KB; stage role aliases as int[512]

    int ia, ib;
    role_split(blockIdx.x, nStage, nTile, &ia, &ib);
    int tid = threadIdx.x;

    if (ia >= 0) {
        int* hist = (int*)Ws;         // [256] (ngrp<=256)
        int* wcur = ((int*)Ws) + 256; // [256]
        if (tid < 256) hist[tid] = 0;
        __syncthreads();

        int q0 = (ia * SB) >> 2;                 // int4-quad base
        int qend = min(q0 + SB / 4, E >> 2);
        int dcache[8], scache[8];
        float wcache[8];

        // pass A: issue ALL loads early; histogram on dst
#pragma unroll
        for (int it = 0; it < 2; ++it) {
            int q = q0 + it * 256 + tid;
            bool ok = (q < qend);
            int4 d4 = ok ? ((const int4*)dstA)[q] : make_int4(-1, -1, -1, -1);
            int4 s4 = ok ? ((const int4*)srcA)[q] : make_int4(0, 0, 0, 0);
            float4 w4 = ok ? ((const float4*)ew)[q] : make_float4(0, 0, 0, 0);
            dcache[it * 4 + 0] = d4.x; dcache[it * 4 + 1] = d4.y;
            dcache[it * 4 + 2] = d4.z; dcache[it * 4 + 3] = d4.w;
            scache[it * 4 + 0] = s4.x; scache[it * 4 + 1] = s4.y;
            scache[it * 4 + 2] = s4.z; scache[it * 4 + 3] = s4.w;
            wcache[it * 4 + 0] = w4.x; wcache[it * 4 + 1] = w4.y;
            wcache[it * 4 + 2] = w4.z; wcache[it * 4 + 3] = w4.w;
#pragma unroll
            for (int j = 0; j < 4; ++j)
                if (dcache[it * 4 + j] >= 0) atomicAdd(&hist[dcache[it * 4 + j] >> GSH_S], 1);
        }
        if (ia == nStage - 1) {
            for (int e = (E & ~3) + tid; e < E; e += 256) atomicAdd(&hist[dstA[e] >> GSH_S], 1);
        }
        __syncthreads();

        // reserve per-group regions
        if (tid < ngrp) {
            int c = hist[tid];
            wcur[tid] = (c > 0) ? atomicAdd(&gcur[tid], c) : 0;
        }
        __syncthreads();

        // pass B phase 1: 8 independent LDS cursor atomics
        int pos[8];
#pragma unroll
        for (int j = 0; j < 8; ++j) {
            int d = dcache[j];
            pos[j] = (d >= 0) ? atomicAdd(&wcur[d >> GSH_S], 1) : GCAP_S;
        }
        // pass B phase 2: stores
#pragma unroll
        for (int j = 0; j < 8; ++j) {
            int d = dcache[j];
            if (d >= 0 && pos[j] < GCAP_S)
                staged[(size_t)(d >> GSH_S) * GCAP_S + pos[j]] =
                    make_int2(((d & (GSPAN_S - 1)) << 17) | scache[j], __float_as_int(wcache[j]));
        }
        if (ia == nStage - 1) {
            for (int e = (E & ~3) + tid; e < E; e += 256) {
                int d = dstA[e];
                int g = d >> GSH_S;
                int p = atomicAdd(&wcur[g], 1);
                if (p < GCAP_S)
                    staged[(size_t)g * GCAP_S + p] =
                        make_int2(((d & (GSPAN_S - 1)) << 17) | srcA[e], __float_as_int(ew[e]));
            }
        }
        return;
    }

    // ---- gemm role: h1 = lrelu(x @ W1 + b1), 64x64 tile, 4x4 micro-tile ----
    int c4 = (tid & 15) * 4;
    int r0 = ib * 64 + (tid >> 4) * 4;
    int rr[4];
#pragma unroll
    for (int i = 0; i < 4; ++i) rr[i] = min(r0 + i, n - 1);

    float acc[4][4] = {};
    for (int ph = 0; ph < 2; ++ph) {
        __syncthreads();
        for (int i = tid; i < 64 * 16; i += 256)
            ((float4*)Ws)[i] = ((const float4*)W1)[ph * 1024 + i];
        __syncthreads();
#pragma unroll 2
        for (int kk = 0; kk < 64; kk += 4) {
            f32x4 av[4], bv[4];
#pragma unroll
            for (int i = 0; i < 4; ++i)
                av[i] = __builtin_nontemporal_load(
                    (const f32x4*)&x[(size_t)rr[i] * NFEATS + ph * 64 + kk]);
#pragma unroll
            for (int q = 0; q < 4; ++q) bv[q] = *(const f32x4*)&Ws[(kk + q) * 64 + c4];
#pragma unroll
            for (int i = 0; i < 4; ++i) {
#pragma unroll
                for (int q = 0; q < 4; ++q) {
                    float a = av[i][q];
#pragma unroll
                    for (int j = 0; j < 4; ++j) acc[i][j] += a * bv[q][j];
                }
            }
        }
    }

#pragma unroll
    for (int i = 0; i < 4; ++i) {
        int rw = r0 + i;
        if (rw >= n) break;
        float4 o;
        float* oa = (float*)&o;
#pragma unroll
        for (int j = 0; j < 4; ++j) {
            float v = acc[i][j] + b1[c4 + j];
            oa[j] = (v > 0.0f) ? v : v * NEG_SLOPE;
        }
        *(float4*)&h1[(size_t)rw * 64 + c4] = o;
    }
}

// ---------------- K3: merged deg/dis + node-sort, packed u64 LDS atomics ----------------
// One block per group. Pass 1: one ds_add_u64 per record (count<<44 | fixpt weighted deg).
// dis = rsqrt(1+deg). Scan hist. Pass 2: scatter (src, ew) node-contiguous.

__global__ __launch_bounds__(512) void degsort_kernel(
    const int* __restrict__ gcur, const int2* __restrict__ staged,
    int2* __restrict__ staged2, float* __restrict__ dis,
    int2* __restrict__ nodeptr, int n) {
    __shared__ unsigned long long pdeg[GSPAN_S];   // 4 KB
    __shared__ int base[GSPAN_S], cur[GSPAN_S];

    int tid = threadIdx.x;
    int g = blockIdx.x;
    pdeg[tid] = 0ull;
    __syncthreads();

    int cnt = min(gcur[g], GCAP_S);
    const int2* sl = staged + (size_t)g * GCAP_S;
    for (int i = tid; i < cnt; i += 512) {
        int2 r = sl[i];
        int dl = r.x >> 17;
        float w = __int_as_float(r.y);
        unsigned long long v = (1ull << CNTSH)
                             + (unsigned long long)(w * FIXSCALE + 0.5f);
        atomicAdd(&pdeg[dl], v);
    }
    __syncthreads();

    unsigned long long p = pdeg[tid];
    int h = (int)(p >> CNTSH);
    float degf = (float)(p & ((1ull << CNTSH) - 1)) * (1.0f / FIXSCALE);

    int node = g * GSPAN_S + tid;
    if (node < n) dis[node] = rsqrtf(1.0f + degf);

    // exclusive scan of h
    base[tid] = h;
    __syncthreads();
    for (int off = 1; off < GSPAN_S; off <<= 1) {
        int t_ = (tid >= off) ? base[tid - off] : 0;
        __syncthreads();
        base[tid] += t_;
        __syncthreads();
    }
    int ex = base[tid] - h;
    cur[tid] = ex;
    __syncthreads();

    if (node < n) nodeptr[node] = make_int2(g * GCAP_S + ex, h);

    int2* out = staged2 + (size_t)g * GCAP_S;
    for (int i = tid; i < cnt; i += 512) {
        int2 r = sl[i];
        int dl = r.x >> 17;
        int pos = atomicAdd(&cur[dl], 1);
        out[pos] = make_int2(r.x & 0x1FFFF, r.y);
    }
}

// ---------------- K4: GEMM2 standalone: t1' = dis ⊙ (h1 @ Wc1) -> bf16 ----------------

__global__ __launch_bounds__(256) void gemm2s_kernel(
    const float* __restrict__ in, const float* __restrict__ W, const float* __restrict__ dis,
    unsigned short* __restrict__ outp, int n) {
    __shared__ __align__(16) float Ws[NHID * 64];
    int tid = threadIdx.x;
    for (int i = tid; i < NHID * 16; i += 256) ((float4*)Ws)[i] = ((const float4*)W)[i];
    __syncthreads();

    int c4 = (tid & 15) * 4;
    int r0 = blockIdx.x * 64 + (tid >> 4) * 4;
    int rr[4];
#pragma unroll
    for (int i = 0; i < 4; ++i) rr[i] = min(r0 + i, n - 1);

    float acc[4][4] = {};
#pragma unroll 2
    for (int kk = 0; kk < NHID; kk += 4) {
        f32x4 av[4], bv[4];
#pragma unroll
        for (int i = 0; i < 4; ++i)
            av[i] = __builtin_nontemporal_load((const f32x4*)&in[(size_t)rr[i] * NHID + kk]);
#pragma unroll
        for (int q = 0; q < 4; ++q) bv[q] = *(const f32x4*)&Ws[(kk + q) * 64 + c4];
#pragma unroll
        for (int i = 0; i < 4; ++i) {
#pragma unroll
            for (int q = 0; q < 4; ++q) {
                float a = av[i][q];
#pragma unroll
                for (int j = 0; j < 4; ++j) acc[i][j] += a * bv[q][j];
            }
        }
    }

#pragma unroll
    for (int i = 0; i < 4; ++i) {
        int rw = r0 + i;
        if (rw >= n) break;
        float dr = dis[rw];
        ushort4 o;
        o.x = f2bfu(dr * acc[i][0]); o.y = f2bfu(dr * acc[i][1]);
        o.z = f2bfu(dr * acc[i][2]); o.w = f2bfu(dr * acc[i][3]);
        *(ushort4*)&outp[(size_t)rw * 64 + c4] = o;
    }
}

// ---------------- K5/K6: aggregation — 16-lane group per edge, 4 edges per load-round ----------------

template <int LAYER>
__global__ __launch_bounds__(256) void agg_kernel(const int2* __restrict__ nodeptr,
                                                  const int2* __restrict__ recs0,
                                                  const unsigned short* __restrict__ tb,
                                                  const float* __restrict__ dis,
                                                  const float* __restrict__ bias,
                                                  unsigned short* __restrict__ outp, int n) {
    int wv = threadIdx.x >> 6;
    int lane = threadIdx.x & 63;
    int node = blockIdx.x * 4 + wv;
    if (node >= n) return;

    int2 np = nodeptr[node];
    int start = np.x, c = np.y;
    int grp = lane >> 4;
    int r16 = lane & 15;
    float di = dis[node];

    f32x4 a0 = {0, 0, 0, 0}, a1 = {0, 0, 0, 0}, a2 = {0, 0, 0, 0}, a3 = {0, 0, 0, 0};

    // self term (weight 1): row already pre-scaled by dis[node]
    if (grp == 0) {
        uint2 uv = *(const uint2*)&tb[(size_t)node * NHID + r16 * 4];
        a0[0] += bflo(uv.x); a0[1] += bfhi(uv.x);
        a0[2] += bflo(uv.y); a0[3] += bfhi(uv.y);
    }

    const i32x2* recs = (const i32x2*)(recs0 + start);
    for (int b = 0; b < c; b += 64) {
        int rem = min(64, c - b);
        i32x2 ent = (lane < rem) ? recs[b + lane] : (i32x2){0, 0};
        for (int k = 0; k < rem; k += 16) {
            int e0 = k + grp, e1 = k + 4 + grp, e2 = k + 8 + grp, e3 = k + 12 + grp;
            int s0 = __shfl(ent[0], e0); float w0 = __int_as_float(__shfl(ent[1], e0));
            int s1 = __shfl(ent[0], e1); float w1 = __int_as_float(__shfl(ent[1], e1));
            int s2 = __shfl(ent[0], e2); float w2 = __int_as_float(__shfl(ent[1], e2));
            int s3 = __shfl(ent[0], e3); float w3 = __int_as_float(__shfl(ent[1], e3));
            uint2 u0 = *(const uint2*)&tb[(size_t)s0 * NHID + r16 * 4];
            uint2 u1 = *(const uint2*)&tb[(size_t)s1 * NHID + r16 * 4];
            uint2 u2 = *(const uint2*)&tb[(size_t)s2 * NHID + r16 * 4];
            uint2 u3 = *(const uint2*)&tb[(size_t)s3 * NHID + r16 * 4];
            a0[0] += w0 * bflo(u0.x); a0[1] += w0 * bfhi(u0.x);
            a0[2] += w0 * bflo(u0.y); a0[3] += w0 * bfhi(u0.y);
            a1[0] += w1 * bflo(u1.x); a1[1] += w1 * bfhi(u1.x);
            a1[2] += w1 * bflo(u1.y); a1[3] += w1 * bfhi(u1.y);
            a2[0] += w2 * bflo(u2.x); a2[1] += w2 * bfhi(u2.x);
            a2[2] += w2 * bflo(u2.y); a2[3] += w2 * bfhi(u2.y);
            a3[0] += w3 * bflo(u3.x); a3[1] += w3 * bfhi(u3.x);
            a3[2] += w3 * bflo(u3.y); a3[3] += w3 * bfhi(u3.y);
        }
    }

    f32x4 acc;
#pragma unroll
    for (int j = 0; j < 4; ++j) acc[j] = (a0[j] + a1[j]) + (a2[j] + a3[j]);
#pragma unroll
    for (int j = 0; j < 4; ++j) {
        acc[j] += __shfl_xor(acc[j], 16);
        acc[j] += __shfl_xor(acc[j], 32);
    }

    if (lane < 16) {
        ushort4 o;
        unsigned short* op = (unsigned short*)&o;
#pragma unroll
        for (int j = 0; j < 4; ++j) {
            float v;
            if (LAYER == 1) {
                v = di * acc[j] + bias[r16 * 4 + j];
                v = (v > 0.0f) ? v : v * NEG_SLOPE;
                v *= di;                        // pre-scale for next layer
            } else {
                v = di * acc[j];
            }
            op[j] = f2bfu(v);
        }
        *(ushort4*)&outp[(size_t)node * NHID + r16 * 4] = o;
    }
}

// ---------------- K7: tail — h3 = lrelu(u2@Wc2+bc2); out = log_softmax(h3@Wo+bo) ----------------

__global__ __launch_bounds__(256) void tail_kernel(const unsigned short* __restrict__ ub,
                                                   const float* __restrict__ Wc2,
                                                   const float* __restrict__ bc2,
                                                   const float* __restrict__ Wo,
                                                   const float* __restrict__ bo,
                                                   float* __restrict__ outp, int n) {
    __shared__ __align__(16) float WsA[NHID * 64];           // 16KB: Wc2 then Wo(2560)
    __shared__ __align__(16) unsigned short hs[64 * 68];     // 8.7KB bf16 h3
    __shared__ float bos[NCLS];

    int tid = threadIdx.x;
    for (int i = tid; i < NHID * 16; i += 256) ((float4*)WsA)[i] = ((const float4*)Wc2)[i];
    __syncthreads();

    int c4 = (tid & 15) * 4;
    int r0l = (tid >> 4) * 4;
    int base = blockIdx.x * 64;

    int rr[4];
#pragma unroll
    for (int i = 0; i < 4; ++i) rr[i] = min(base + r0l + i, n - 1);

    float acc[4][4] = {};
#pragma unroll 2
    for (int kk = 0; kk < NHID; kk += 4) {
        f32x4 av[4], bv[4];
#pragma unroll
        for (int i = 0; i < 4; ++i) {
            ushort4 uv = *(const ushort4*)&ub[(size_t)rr[i] * NHID + kk];
            av[i][0] = bf2f(uv.x); av[i][1] = bf2f(uv.y);
            av[i][2] = bf2f(uv.z); av[i][3] = bf2f(uv.w);
        }
#pragma unroll
        for (int q = 0; q < 4; ++q) bv[q] = *(const f32x4*)&WsA[(kk + q) * 64 + c4];
#pragma unroll
        for (int i = 0; i < 4; ++i) {
#pragma unroll
            for (int q = 0; q < 4; ++q) {
                float a = av[i][q];
#pragma unroll
                for (int j = 0; j < 4; ++j) acc[i][j] += a * bv[q][j];
            }
        }
    }

#pragma unroll
    for (int i = 0; i < 4; ++i) {
#pragma unroll
        for (int j = 0; j < 4; ++j) {
            float v = acc[i][j] + bc2[c4 + j];
            v = (v > 0.0f) ? v : v * NEG_SLOPE;
            hs[(r0l + i) * 68 + c4 + j] = f2bfu(v);
        }
    }
    __syncthreads();

    // reload WsA[0..2559] = Wo (64x40)
    for (int i = tid; i < NHID * NCLS / 4; i += 256) ((float4*)WsA)[i] = ((const float4*)Wo)[i];
    if (tid < NCLS) bos[tid] = bo[tid];
    __syncthreads();

    // phase 2: row = tid>>2 (0..63), cols c0..c0+9
    int row = tid >> 2;
    int c0 = (tid & 3) * 10;
    int node = base + row;

    float z[10];
#pragma unroll
    for (int j = 0; j < 10; ++j) z[j] = 0.0f;

#pragma unroll 2
    for (int k0 = 0; k0 < NHID; k0 += 4) {
        ushort4 hv = *(const ushort4*)&hs[row * 68 + k0];
        float h0 = bf2f(hv.x), h1 = bf2f(hv.y), h2 = bf2f(hv.z), h3 = bf2f(hv.w);
        const float* w0 = &WsA[(k0 + 0) * NCLS + c0];
        const float* w1 = &WsA[(k0 + 1) * NCLS + c0];
        const float* w2 = &WsA[(k0 + 2) * NCLS + c0];
        const float* w3 = &WsA[(k0 + 3) * NCLS + c0];
#pragma unroll
        for (int j = 0; j < 10; ++j)
            z[j] += h0 * w0[j] + h1 * w1[j] + h2 * w2[j] + h3 * w3[j];
    }
#pragma unroll
    for (int j = 0; j < 10; ++j) z[j] += bos[c0 + j];

    float m = z[0];
#pragma unroll
    for (int j = 1; j < 10; ++j) m = fmaxf(m, z[j]);
    m = fmaxf(m, __shfl_xor(m, 1));
    m = fmaxf(m, __shfl_xor(m, 2));

    float s = 0.0f;
#pragma unroll
    for (int j = 0; j < 10; ++j) s += expf(z[j] - m);
    s += __shfl_xor(s, 1);
    s += __shfl_xor(s, 2);
    float ls = logf(s);

    if (node < n) {
#pragma unroll
        for (int j = 0; j < 10; ++j)
            outp[(size_t)node * NCLS + c0 + j] = z[j] - m - ls;
    }
}

// ---------------- launch ----------------

extern "C" void kernel_launch(void* const* d_in, const int* in_sizes, int n_in,
                              void* d_out, int out_size, void* d_ws, size_t ws_size,
                              hipStream_t stream) {
    const float* x   = (const float*)d_in[0];
    const int*   ei  = (const int*)d_in[1];   // [2, E] flat
    const float* ew  = (const float*)d_in[2];
    const float* W1  = (const float*)d_in[3];
    const float* b1  = (const float*)d_in[4];
    const float* Wc1 = (const float*)d_in[5];
    const float* bc1 = (const float*)d_in[6];
    const float* Wc2 = (const float*)d_in[7];
    const float* bc2 = (const float*)d_in[8];
    const float* Wo  = (const float*)d_in[9];
    const float* bo  = (const float*)d_in[10];
    float* out = (float*)d_out;

    const int N = in_sizes[0] / NFEATS;
    const int E = in_sizes[1] / 2;
    const int* src = ei;
    const int* dst = ei + E;

    const int ngrp   = (N + GSPAN_S - 1) >> GSH_S;    // 196
    const int nStage = (E + SB - 1) / SB;             // 782
    const int nTile  = (N + 63) / 64;                 // 1563
    const int aggBlocks = (N + 3) / 4;

    // workspace layout (~81 MB)
    float*          bufA  = (float*)d_ws;                          // N*64 f32 (h1)
    unsigned short* t1b   = (unsigned short*)(bufA + (size_t)N * NHID);  // N*64 bf16 (t1', later u2)
    unsigned short* h2b   = t1b + (size_t)N * NHID;                // N*64 bf16 (h2')
    int2*  staged  = (int2*)(h2b + (size_t)N * NHID);              // ngrp*GCAP_S
    int2*  staged2 = staged + (size_t)ngrp * GCAP_S;               // ngrp*GCAP_S
    float* dis     = (float*)(staged2 + (size_t)ngrp * GCAP_S);    // N
    int*   gcur    = (int*)(dis + N);                              // ngrp (pad to 8B)
    int2*  nodeptr = (int2*)(gcur + ((ngrp + 1) & ~1));            // N

    // K1: zero group cursors
    hipMemsetAsync(gcur, 0, ngrp * sizeof(int), stream);

    // K2: coarse staged binning + h1 = lrelu(x@W1+b1) -> bufA
    stage_gemm1_kernel<<<nStage + nTile, 256, 0, stream>>>(
        src, dst, ew, gcur, staged, E, nStage, ngrp, x, W1, b1, bufA, N, nTile);

    // K3: merged deg/dis + node-sort (u64 packed pass 1) -> staged2, nodeptr
    degsort_kernel<<<ngrp, 512, 0, stream>>>(gcur, staged, staged2, dis, nodeptr, N);

    // K4: t1' = dis ⊙ (h1@Wc1) -> t1b (bf16)
    gemm2s_kernel<<<nTile, 256, 0, stream>>>(bufA, Wc1, dis, t1b, N);

    // K5: h2' = dis ⊙ lrelu(dis*(agg) + bc1) -> h2b (bf16)
    agg_kernel<1><<<aggBlocks, 256, 0, stream>>>(nodeptr, staged2, t1b, dis, bc1, h2b, N);

    // K6: u2 = dis*(agg(h2')) -> t1b reused (bf16)
    agg_kernel<2><<<aggBlocks, 256, 0, stream>>>(nodeptr, staged2, h2b, dis, nullptr, t1b, N);

    // K7: tail
    tail_kernel<<<nTile, 256, 0, stream>>>(t1b, Wc2, bc2, Wo, bo, out, N);
}